// Round 3
// baseline (714.059 us; speedup 1.0000x reference)
//
#include <hip/hip_runtime.h>
#include <stdint.h>

typedef float f32x4 __attribute__((ext_vector_type(4)));

// Fully f32 fused MLP, 64 rows/block, 256 threads. No MFMA, no bf16 —
// diagnostic baseline to bisect the round-2 numerical bug.
__global__ __launch_bounds__(256) void mlp_kernel(
    const float* __restrict__ data,
    const float* __restrict__ W1, const float* __restrict__ b1,
    const float* __restrict__ W2, const float* __restrict__ b2,
    const float* __restrict__ W3, const float* __restrict__ b3,
    const float* __restrict__ Wout, const float* __restrict__ bout,
    float* __restrict__ proj)
{
    __shared__ __align__(16) char smem[51200];
    float* a_s  = (float*)(smem);            // L1: data tile [64][68], 17408 B
    float* w1_s = (float*)(smem + 17408);    // L1: W1 tile [64][132], 33792 B -> 51200
    float* h1s  = (float*)(smem);            // L2: [64][132], 33792 B
    float* w2s  = (float*)(smem + 33792);    // L2: W2 half [64][64], 16384 B -> 50176
    float* h2s  = (float*)(smem);            // L3: [64][68], 17408 B
    float* w3s  = (float*)(smem + 17408);    // L3: W3 [64][32], 8192 B -> 25600

    const int tid = threadIdx.x;
    const size_t row0 = (size_t)blockIdx.x * 64;

    // ---------------- Layer 1: pure f32 VALU, 13 k-tiles of 64 ----------------
    const int srow = tid >> 2, sq = tid & 3;   // staging: row 0..63, quarter 0..3
    const int rg = tid >> 4,  cg = tid & 15;   // compute: rows rg*4..+3, cols cg*8..+7

    float acc[4][8];
    #pragma unroll
    for (int r = 0; r < 4; ++r)
        #pragma unroll
        for (int j = 0; j < 8; ++j) acc[r][j] = 0.f;

    for (int it = 0; it < 13; ++it) {
        const int kbase = it * 64;
        // stage data tile [64][64] -> a_s stride 68
        #pragma unroll
        for (int j = 0; j < 4; ++j) {
            int col = kbase + sq*16 + j*4;
            f32x4 v = (f32x4){0.f, 0.f, 0.f, 0.f};
            if (col < 784) v = *(const f32x4*)(data + (row0 + srow)*784 + col);
            *(f32x4*)(a_s + srow*68 + sq*16 + j*4) = v;
        }
        // stage W1 rows kbase..kbase+63 -> w1_s stride 132 (W1 is [784][128] row-major)
        {
            const int gk = kbase + srow;
            #pragma unroll
            for (int j = 0; j < 8; ++j) {
                f32x4 v = (f32x4){0.f, 0.f, 0.f, 0.f};
                if (gk < 784) v = *(const f32x4*)(W1 + (size_t)gk*128 + sq*32 + j*4);
                *(f32x4*)(w1_s + srow*132 + sq*32 + j*4) = v;
            }
        }
        __syncthreads();
        #pragma unroll 4
        for (int kk = 0; kk < 64; ++kk) {
            f32x4 w0 = *(const f32x4*)(w1_s + kk*132 + cg*8);
            f32x4 w1v = *(const f32x4*)(w1_s + kk*132 + cg*8 + 4);
            #pragma unroll
            for (int r = 0; r < 4; ++r) {
                float a = a_s[(rg*4 + r)*68 + kk];
                #pragma unroll
                for (int c = 0; c < 4; ++c) {
                    acc[r][c]     += a * w0[c];
                    acc[r][4 + c] += a * w1v[c];
                }
            }
        }
        __syncthreads();
    }
    // epilogue: bias + relu -> h1s [64][132]
    #pragma unroll
    for (int r = 0; r < 4; ++r) {
        const int m = rg*4 + r;
        #pragma unroll
        for (int j = 0; j < 8; ++j) {
            const int col = cg*8 + j;
            float v = acc[r][j] + b1[col];
            h1s[m*132 + col] = v > 0.f ? v : 0.f;
        }
    }
    // stage W2 phase 0 (rows 0..63)
    #pragma unroll
    for (int j = 0; j < 4; ++j) {
        int wi = j*1024 + tid*4;
        *(f32x4*)(w2s + wi) = *(const f32x4*)(W2 + wi);
    }
    __syncthreads();

    // ---------------- Layer 2: f32 VALU, two 64-K phases ----------------
    const int m2 = tid >> 2, nq = tid & 3;
    float h2a[16];
    #pragma unroll
    for (int i = 0; i < 16; ++i) h2a[i] = b2[nq*16 + i];
    #pragma unroll
    for (int p = 0; p < 2; ++p) {
        if (p == 1) {
            __syncthreads();
            #pragma unroll
            for (int j = 0; j < 4; ++j) {
                int wi = j*1024 + tid*4;
                *(f32x4*)(w2s + wi) = *(const f32x4*)(W2 + 4096 + wi);
            }
            __syncthreads();
        }
        for (int q = 0; q < 16; ++q) {
            f32x4 hq = *(const f32x4*)(h1s + m2*132 + p*64 + q*4);
            #pragma unroll
            for (int kk = 0; kk < 4; ++kk) {
                #pragma unroll
                for (int i = 0; i < 4; ++i) {
                    f32x4 wv = *(const f32x4*)(w2s + (q*4 + kk)*64 + nq*16 + i*4);
                    #pragma unroll
                    for (int c = 0; c < 4; ++c) h2a[i*4 + c] += hq[kk] * wv[c];
                }
            }
        }
    }
    __syncthreads();
    // relu(h2) -> h2s [64][68]; stage W3
    #pragma unroll
    for (int i = 0; i < 4; ++i) {
        f32x4 v;
        #pragma unroll
        for (int c = 0; c < 4; ++c) { float x = h2a[i*4 + c]; v[c] = x > 0.f ? x : 0.f; }
        *(f32x4*)(h2s + m2*68 + nq*16 + i*4) = v;
    }
    #pragma unroll
    for (int j = 0; j < 2; ++j) {
        int wi = j*1024 + tid*4;
        *(f32x4*)(w3s + wi) = *(const f32x4*)(W3 + wi);
    }
    __syncthreads();

    // ---------------- Layer 3: f32 VALU ----------------
    const int m3 = tid >> 2, nq3 = tid & 3;
    float h3a[8];
    #pragma unroll
    for (int i = 0; i < 8; ++i) h3a[i] = b3[nq3*8 + i];
    for (int q = 0; q < 16; ++q) {
        f32x4 hq = *(const f32x4*)(h2s + m3*68 + q*4);
        #pragma unroll
        for (int kk = 0; kk < 4; ++kk) {
            #pragma unroll
            for (int i2 = 0; i2 < 2; ++i2) {
                f32x4 wv = *(const f32x4*)(w3s + (q*4 + kk)*32 + nq3*8 + i2*4);
                #pragma unroll
                for (int c = 0; c < 4; ++c) h3a[i2*4 + c] += hq[kk] * wv[c];
            }
        }
    }
    // ---------------- Layer 4: relu + Wout, 4-lane shuffle reduce ----------------
    float p0 = 0.f, p1 = 0.f;
    #pragma unroll
    for (int i = 0; i < 8; ++i) {
        const int k = nq3*8 + i;
        float h = h3a[i] > 0.f ? h3a[i] : 0.f;
        p0 += h * Wout[k*2 + 0];
        p1 += h * Wout[k*2 + 1];
    }
    p0 += __shfl_xor(p0, 1); p0 += __shfl_xor(p0, 2);
    p1 += __shfl_xor(p1, 1); p1 += __shfl_xor(p1, 2);
    if (nq3 == 0) {
        proj[(row0 + m3)*2 + 0] = p0 + bout[0];
        proj[(row0 + m3)*2 + 1] = p1 + bout[1];
    }
}

// gather + squared distance, f32 out
__global__ __launch_bounds__(256) void dist_kernel(
    const float* __restrict__ proj, const int* __restrict__ idxs,
    float* __restrict__ out, int total)
{
    int gid = blockIdx.x * 256 + threadIdx.x;
    if (gid >= total) return;
    unsigned i = (unsigned)gid / 10u;
    unsigned j = (unsigned)idxs[gid];
    float dx = proj[i*2 + 0] - proj[j*2 + 0];
    float dy = proj[i*2 + 1] - proj[j*2 + 1];
    out[gid] = dx*dx + dy*dy;
}

extern "C" void kernel_launch(void* const* d_in, const int* in_sizes, int n_in,
                              void* d_out, int out_size, void* d_ws, size_t ws_size,
                              hipStream_t stream)
{
    const float* data = (const float*)d_in[0];
    const int*   idxs = (const int*)d_in[1];
    const float* W1   = (const float*)d_in[2];
    const float* b1   = (const float*)d_in[3];
    const float* W2   = (const float*)d_in[4];
    const float* b2   = (const float*)d_in[5];
    const float* W3   = (const float*)d_in[6];
    const float* b3   = (const float*)d_in[7];
    const float* Wout = (const float*)d_in[8];
    const float* bout = (const float*)d_in[9];

    const int N = in_sizes[0] / 784;           // 200000, divisible by 64
    float* proj = (float*)d_ws;                // N*2 f32 = 1,600,000 B (ws >= 2MB proven r2)

    mlp_kernel<<<N / 64, 256, 0, stream>>>(data, W1, b1, W2, b2, W3, b3, Wout, bout, proj);
    dist_kernel<<<(N*10 + 255) / 256, 256, 0, stream>>>(proj, idxs, (float*)d_out, N*10);
}

// Round 4
// 691.312 us; speedup vs baseline: 1.0329x; 1.0329x over previous
//
#include <hip/hip_runtime.h>
#include <stdint.h>

typedef float f32x4 __attribute__((ext_vector_type(4)));

// Fully f32 fused MLP, 64 rows/block, 256 threads, 4 waves.
// Round-4: bank-conflict-free layouts + 4 blocks/CU occupancy (LDS 37888B).
__global__ __launch_bounds__(256, 4) void mlp_kernel(
    const float* __restrict__ data,
    const float* __restrict__ W1, const float* __restrict__ b1,
    const float* __restrict__ W2, const float* __restrict__ b2,
    const float* __restrict__ W3, const float* __restrict__ b3,
    const float* __restrict__ Wout, const float* __restrict__ bout,
    float* __restrict__ proj)
{
    __shared__ __align__(16) char smem[37888];
    float* a_s  = (float*)(smem);            // L1: data tile [64][32] swizzled, 8192 B
    float* w1_s = (float*)(smem + 8192);     // L1: W1 tile [32][132], 16896 B -> 25088
    float* h1s  = (float*)(smem);            // L2: [64][132], 33792 B
    float* w2s  = (float*)(smem + 33792);    // L2: W2 16-k phase [16][64], 4096 B -> 37888
    float* h2s  = (float*)(smem);            // L3: [64][68], 17408 B
    float* w3s  = (float*)(smem + 17408);    // L3: W3 [64][32], 8192 B -> 25600

    const int tid = threadIdx.x;
    const size_t row0 = (size_t)blockIdx.x * 64;

    // ---------------- Layer 1: f32 VALU, 25 k-tiles of 32 ----------------
    const int ty = tid & 15;     // compute: rows ty*4..+3
    const int tx = tid >> 4;     // compute: cols tx*8..+7

    float acc[4][8];
    #pragma unroll
    for (int r = 0; r < 4; ++r)
        #pragma unroll
        for (int c = 0; c < 8; ++c) acc[r][c] = 0.f;

    for (int it = 0; it < 25; ++it) {
        const int kbase = it * 32;
        // stage data tile -> a_s [64][32], XOR-swizzled on 16B groups:
        // elem (m, k): float off = m*32 + ((k>>2) ^ ((m>>2)&7))*4 + (k&3)
        {
            const int sr = tid >> 2, q = tid & 3;
            #pragma unroll
            for (int j = 0; j < 2; ++j) {
                const int kg = q + 4*j;          // 16B group 0..7
                const int col = kbase + kg*4;
                f32x4 v = (f32x4){0.f, 0.f, 0.f, 0.f};
                if (col < 784) v = *(const f32x4*)(data + (row0 + sr)*784 + col);
                *(f32x4*)(a_s + sr*32 + ((kg ^ ((sr >> 2) & 7)) << 2)) = v;
            }
        }
        // stage W1 rows kbase..+31 -> w1_s [32][132] (no swizzle; reads conflict-free)
        {
            const int kr = tid >> 3, c8 = tid & 7;
            const int gk = kbase + kr;
            #pragma unroll
            for (int j = 0; j < 4; ++j) {
                const int col = c8*4 + 32*j;     // 0..124
                f32x4 v = (f32x4){0.f, 0.f, 0.f, 0.f};
                if (gk < 784) v = *(const f32x4*)(W1 + (size_t)gk*128 + col);
                *(f32x4*)(w1_s + kr*132 + col) = v;
            }
        }
        __syncthreads();
        #pragma unroll
        for (int kt = 0; kt < 8; ++kt) {         // 4-k chunks
            f32x4 av[4];
            #pragma unroll
            for (int r = 0; r < 4; ++r)
                av[r] = *(const f32x4*)(a_s + (ty*4 + r)*32 + ((kt ^ (ty & 7)) << 2));
            #pragma unroll
            for (int kk = 0; kk < 4; ++kk) {
                f32x4 w0  = *(const f32x4*)(w1_s + (kt*4 + kk)*132 + tx*8);
                f32x4 w1v = *(const f32x4*)(w1_s + (kt*4 + kk)*132 + tx*8 + 4);
                #pragma unroll
                for (int r = 0; r < 4; ++r) {
                    const float a = av[r][kk];
                    #pragma unroll
                    for (int c = 0; c < 4; ++c) {
                        acc[r][c]     += a * w0[c];
                        acc[r][4 + c] += a * w1v[c];
                    }
                }
            }
        }
        __syncthreads();
    }
    // epilogue: bias + relu -> h1s [64][132]
    #pragma unroll
    for (int r = 0; r < 4; ++r) {
        const int m = ty*4 + r;
        #pragma unroll
        for (int c = 0; c < 8; ++c) {
            const int col = tx*8 + c;
            float v = acc[r][c] + b1[col];
            h1s[m*132 + col] = v > 0.f ? v : 0.f;
        }
    }

    // ---------------- Layer 2: f32 VALU, 8 phases of 16 k ----------------
    const int m2 = tid >> 2, nq = tid & 3;
    float h2a[16];
    #pragma unroll
    for (int i = 0; i < 16; ++i) h2a[i] = b2[nq*16 + i];
    for (int p = 0; p < 8; ++p) {
        if (p) __syncthreads();                  // prior w2s reads done
        // stage W2 rows p*16..+15 -> w2s [16][64] (1024 f32, 1 f32x4/thread)
        *(f32x4*)(w2s + tid*4) = *(const f32x4*)(W2 + p*1024 + tid*4);
        __syncthreads();                         // also covers h1s epilogue at p==0
        #pragma unroll
        for (int q = 0; q < 4; ++q) {
            f32x4 hq = *(const f32x4*)(h1s + m2*132 + p*16 + q*4);
            #pragma unroll
            for (int kk = 0; kk < 4; ++kk) {
                #pragma unroll
                for (int i = 0; i < 4; ++i) {
                    f32x4 wv = *(const f32x4*)(w2s + (q*4 + kk)*64 + nq*16 + i*4);
                    #pragma unroll
                    for (int c = 0; c < 4; ++c) h2a[i*4 + c] += hq[kk] * wv[c];
                }
            }
        }
    }
    __syncthreads();
    // relu(h2) -> h2s [64][68]; stage W3
    #pragma unroll
    for (int i = 0; i < 4; ++i) {
        f32x4 v;
        #pragma unroll
        for (int c = 0; c < 4; ++c) { float x = h2a[i*4 + c]; v[c] = x > 0.f ? x : 0.f; }
        *(f32x4*)(h2s + m2*68 + nq*16 + i*4) = v;
    }
    #pragma unroll
    for (int j = 0; j < 2; ++j) {
        int wi = j*1024 + tid*4;
        *(f32x4*)(w3s + wi) = *(const f32x4*)(W3 + wi);
    }
    __syncthreads();

    // ---------------- Layer 3: f32 VALU ----------------
    const int m3 = tid >> 2, nq3 = tid & 3;
    float h3a[8];
    #pragma unroll
    for (int i = 0; i < 8; ++i) h3a[i] = b3[nq3*8 + i];
    for (int q = 0; q < 16; ++q) {
        f32x4 hq = *(const f32x4*)(h2s + m3*68 + q*4);
        #pragma unroll
        for (int kk = 0; kk < 4; ++kk) {
            #pragma unroll
            for (int i2 = 0; i2 < 2; ++i2) {
                f32x4 wv = *(const f32x4*)(w3s + (q*4 + kk)*32 + nq3*8 + i2*4);
                #pragma unroll
                for (int c = 0; c < 4; ++c) h3a[i2*4 + c] += hq[kk] * wv[c];
            }
        }
    }
    // ---------------- Layer 4: relu + Wout, 4-lane shuffle reduce ----------------
    float p0 = 0.f, p1 = 0.f;
    #pragma unroll
    for (int i = 0; i < 8; ++i) {
        const int k = nq3*8 + i;
        float h = h3a[i] > 0.f ? h3a[i] : 0.f;
        p0 += h * Wout[k*2 + 0];
        p1 += h * Wout[k*2 + 1];
    }
    p0 += __shfl_xor(p0, 1); p0 += __shfl_xor(p0, 2);
    p1 += __shfl_xor(p1, 1); p1 += __shfl_xor(p1, 2);
    if (nq3 == 0) {
        proj[(row0 + m3)*2 + 0] = p0 + bout[0];
        proj[(row0 + m3)*2 + 1] = p1 + bout[1];
    }
}

// gather + squared distance, f32 out
__global__ __launch_bounds__(256) void dist_kernel(
    const float* __restrict__ proj, const int* __restrict__ idxs,
    float* __restrict__ out, int total)
{
    int gid = blockIdx.x * 256 + threadIdx.x;
    if (gid >= total) return;
    unsigned i = (unsigned)gid / 10u;
    unsigned j = (unsigned)idxs[gid];
    float dx = proj[i*2 + 0] - proj[j*2 + 0];
    float dy = proj[i*2 + 1] - proj[j*2 + 1];
    out[gid] = dx*dx + dy*dy;
}

extern "C" void kernel_launch(void* const* d_in, const int* in_sizes, int n_in,
                              void* d_out, int out_size, void* d_ws, size_t ws_size,
                              hipStream_t stream)
{
    const float* data = (const float*)d_in[0];
    const int*   idxs = (const int*)d_in[1];
    const float* W1   = (const float*)d_in[2];
    const float* b1   = (const float*)d_in[3];
    const float* W2   = (const float*)d_in[4];
    const float* b2   = (const float*)d_in[5];
    const float* W3   = (const float*)d_in[6];
    const float* b3   = (const float*)d_in[7];
    const float* Wout = (const float*)d_in[8];
    const float* bout = (const float*)d_in[9];

    const int N = in_sizes[0] / 784;           // 200000, divisible by 64
    float* proj = (float*)d_ws;                // N*2 f32 = 1,600,000 B

    mlp_kernel<<<N / 64, 256, 0, stream>>>(data, W1, b1, W2, b2, W3, b3, Wout, bout, proj);
    dist_kernel<<<(N*10 + 255) / 256, 256, 0, stream>>>(proj, idxs, (float*)d_out, N*10);
}